// Round 13
// baseline (1201.121 us; speedup 1.0000x reference)
//
#include <hip/hip_runtime.h>
#include <hip/hip_bf16.h>

typedef unsigned short u16;
typedef __attribute__((ext_vector_type(4))) float f32x4;
typedef __attribute__((ext_vector_type(8))) short short8;
typedef __attribute__((ext_vector_type(8))) u16 us8;

// Geometry (fixed): B=64, N=256, DIM=2048, H=8, D=256; M=B*N=16384; qkvN=6144

__device__ __forceinline__ u16 f2bf(float f) {
  union { float f; unsigned u; } v; v.f = f;
  unsigned r = v.u + 0x7fffu + ((v.u >> 16) & 1u);   // RNE, finite inputs
  return (u16)(r >> 16);
}
__device__ __forceinline__ float bf2f(u16 h) {
  union { unsigned u; float f; } v; v.u = ((unsigned)h) << 16; return v.f;
}
// non-temporal (streaming) stores: bypass L2/L3 write-allocate so resident
// operand panels (x_hi, w) are not evicted by output streams.  Cache hint
// only -- values/coherence unchanged -> bit-exact output.
__device__ __forceinline__ void nts(u16* p, u16 v) { __builtin_nontemporal_store(v, p); }
__device__ __forceinline__ void ntsf(float* p, float v) { __builtin_nontemporal_store(v, p); }

__global__ void beacon_kernel(float* __restrict__ out, float val, int n) {
  int stride = gridDim.x * blockDim.x;
  for (int i = blockIdx.x * blockDim.x + threadIdx.x; i < n; i += stride)
    out[i] = val;
}

__global__ void split_kernel(const float* __restrict__ in, u16* __restrict__ hi,
                             u16* __restrict__ lo, int n4) {
  int stride = gridDim.x * blockDim.x;
  for (int i = blockIdx.x * blockDim.x + threadIdx.x; i < n4; i += stride) {
    f32x4 v = __builtin_nontemporal_load(&((const f32x4*)in)[i]);   // read-once stream
    ushort4 h;
    h.x = f2bf(v[0]); h.y = f2bf(v[1]); h.z = f2bf(v[2]); h.w = f2bf(v[3]);
    ((ushort4*)hi)[i] = h;                    // normal store: WANT in L3 (re-read by GEMMs)
    if (lo) {
      ushort4 l;
      l.x = f2bf(v[0] - bf2f(h.x)); l.y = f2bf(v[1] - bf2f(h.y));
      l.z = f2bf(v[2] - bf2f(h.z)); l.w = f2bf(v[3] - bf2f(h.w));
      ((ushort4*)lo)[i] = l;
    }
  }
}

#define SCHED0 __builtin_amdgcn_sched_barrier(0)
#define LGKM0 do { asm volatile("s_waitcnt lgkmcnt(0)" ::: "memory"); SCHED0; } while (0)
#define VM0 do { asm volatile("s_waitcnt vmcnt(0)" ::: "memory"); } while (0)
#define BAR __builtin_amdgcn_s_barrier()

// ====== 256x256 4-phase bf16 NT GEMM (round-6 schedule; epilogue stores NT) ======
template<int EPI>
__global__ __launch_bounds__(512, 2)
void gemm256(const u16* __restrict__ A0, const u16* __restrict__ A1,
             const u16* __restrict__ B0, const u16* __restrict__ B1,
             int ldA, int ldB, int ntiles, int segShift, int gridMx,
             u16* __restrict__ qh, u16* __restrict__ ql,
             u16* __restrict__ kh, u16* __restrict__ kl,
             u16* __restrict__ vv,
             float* __restrict__ fout, const float* __restrict__ bias) {
  extern __shared__ __align__(16) u16 lds[];   // 128 KiB: 2 dbuf x (A+B)[256][64]

  const int tid = threadIdx.x;
  const int w = tid >> 6, lane = tid & 63;
  const int wr = w >> 2, wcn = w & 3;          // 2M x 4N waves, 128x64 out each
  const int l15 = lane & 15, g = lane >> 4;
  const int rsw = l15 & 7;                     // read-side slot XOR (row&7)
  const int scol = (((tid & 7) ^ ((tid >> 3) & 7)) << 3);  // pre-swz src col

  int bid = blockIdx.x, cpx = gridDim.x >> 3;
  int swz = (bid & 7) * cpx + (bid >> 3);
  int m0 = (swz % gridMx) << 8;
  int n0 = (swz / gridMx) << 8;

  const u16* As[2] = {A0, A1};
  const u16* Bs[2] = {B0, B1};
  const int kmask = (1 << segShift) - 1;

  f32x4 acc[8][4] = {};
  short8 af[8], bA[4], bB[4];

  auto stageA = [&](int db, const u16* Ab, int k0) {
    #pragma unroll
    for (int s = 0; s < 4; ++s) {
      const u16* src = Ab + (size_t)(m0 + s * 64 + (tid >> 3)) * ldA + k0 + scol;
      u16* dst = lds + db * 32768 + s * 4096 + tid * 8;
      __builtin_amdgcn_global_load_lds(
          (const __attribute__((address_space(1))) unsigned*)src,
          (__attribute__((address_space(3))) unsigned*)dst, 16, 0, 0);
    }
  };
  auto stageB = [&](int db, const u16* Bb, int k0) {
    #pragma unroll
    for (int s = 0; s < 4; ++s) {
      const u16* src = Bb + (size_t)(n0 + s * 64 + (tid >> 3)) * ldB + k0 + scol;
      u16* dst = lds + db * 32768 + 16384 + s * 4096 + tid * 8;
      __builtin_amdgcn_global_load_lds(
          (const __attribute__((address_space(1))) unsigned*)src,
          (__attribute__((address_space(3))) unsigned*)dst, 16, 0, 0);
    }
  };
  auto readA = [&](int db, int MH) {
    #pragma unroll
    for (int f = 0; f < 4; ++f) {
      int row = wr * 128 + MH * 64 + f * 16 + l15;
      #pragma unroll
      for (int kk = 0; kk < 2; ++kk) {
        int sl = (kk * 4 + g) ^ rsw;
        af[f * 2 + kk] = *(const short8*)(lds + db * 32768 + row * 64 + sl * 8);
      }
    }
  };
  auto readB = [&](short8* bf, int db, int NH) {
    #pragma unroll
    for (int f = 0; f < 2; ++f) {
      int row = wcn * 64 + NH * 32 + f * 16 + l15;
      #pragma unroll
      for (int kk = 0; kk < 2; ++kk) {
        int sl = (kk * 4 + g) ^ rsw;
        bf[f * 2 + kk] = *(const short8*)(lds + db * 32768 + 16384 + row * 64 + sl * 8);
      }
    }
  };

#define MMA_QUAD(MH, NH, BF)                                                   \
  __builtin_amdgcn_s_setprio(1);                                               \
  _Pragma("unroll") for (int f = 0; f < 4; ++f)                                \
    _Pragma("unroll") for (int j = 0; j < 2; ++j)                              \
      _Pragma("unroll") for (int kk = 0; kk < 2; ++kk)                         \
        acc[(MH) * 4 + f][(NH) * 2 + j] =                                      \
            __builtin_amdgcn_mfma_f32_16x16x32_bf16(                           \
                af[f * 2 + kk], BF[j * 2 + kk],                                \
                acc[(MH) * 4 + f][(NH) * 2 + j], 0, 0, 0);                     \
  __builtin_amdgcn_s_setprio(0)

  const int T = ntiles;
  stageA(0, As[0], 0);
  stageB(0, Bs[0], 0);
  VM0;
  BAR; SCHED0;

  for (int t = 0; t < T - 1; ++t) {
    int cur = t & 1, nxt = cur ^ 1;
    int t1 = t + 1;
    const u16* An = As[t1 >> segShift];
    const u16* Bn = Bs[t1 >> segShift];
    int kn = (t1 & kmask) << 6;
    readA(cur, 0);
    readB(bA, cur, 0);
    stageA(nxt, An, kn);
    BAR; LGKM0;
    MMA_QUAD(0, 0, bA);
    BAR; SCHED0;
    readB(bB, cur, 1);
    stageB(nxt, Bn, kn);
    BAR; LGKM0;
    MMA_QUAD(0, 1, bB);
    BAR; SCHED0;
    readA(cur, 1);
    BAR; LGKM0;
    MMA_QUAD(1, 1, bB);
    BAR; SCHED0;
    MMA_QUAD(1, 0, bA);
    VM0;
    BAR; SCHED0;
  }
  {
    int cur = (T - 1) & 1;
    readA(cur, 0);
    readB(bA, cur, 0);
    LGKM0;
    MMA_QUAD(0, 0, bA);
    readB(bB, cur, 1);
    LGKM0;
    MMA_QUAD(0, 1, bB);
    readA(cur, 1);
    LGKM0;
    MMA_QUAD(1, 1, bB);
    MMA_QUAD(1, 0, bA);
  }
#undef MMA_QUAD

  #pragma unroll
  for (int i = 0; i < 8; ++i)
    #pragma unroll
    for (int j = 0; j < 4; ++j)
      #pragma unroll
      for (int rr = 0; rr < 4; ++rr) {
        int gm = m0 + wr * 128 + i * 16 + g * 4 + rr;
        int gn = n0 + wcn * 64 + j * 16 + l15;
        float val = acc[i][j][rr];
        if constexpr (EPI == 0) {
          int b = gm >> 8, tok = gm & 255;
          int sel = gn >> 11, head = (gn >> 8) & 7, col = gn & 255;
          size_t addr = (((size_t)b * 8 + head) * 256 + tok) * 256 + col;
          u16 h = f2bf(val), lo = f2bf(val - bf2f(h));
          if (sel == 0) { nts(&qh[addr], h); nts(&ql[addr], lo); }
          else          { nts(&kh[addr], h); nts(&kl[addr], lo); }
        } else if constexpr (EPI == 1) {
          int b = gm >> 8, tok = gm & 255;
          int head = (gn >> 8) & 7, col = gn & 255;
          size_t addr = (((size_t)b * 8 + head) * 256 + tok) * 256 + col;
          nts(&vv[addr], f2bf(val));
        } else {
          ntsf(&fout[(size_t)gm * 2048 + gn], val + bias[gn]);
        }
      }
}

// ====== fully fused attention: logits + cross-wave softmax + PV (r12 verbatim) ======
__global__ __launch_bounds__(256)
void fused_attn(const u16* __restrict__ kh, const u16* __restrict__ kl,
                const u16* __restrict__ qh, const u16* __restrict__ ql,
                const u16* __restrict__ vT, u16* __restrict__ aout) {
  __shared__ __align__(16) u16 sA[2][2048];       // 64x32 dbuf (k rows)
  __shared__ __align__(16) u16 sB[2][8192];       // 256x32 dbuf (q / vT)
  __shared__ __align__(16) u16 sP[64 * 276];      // P, padded
  __shared__ float red[2][4][64];                 // partial max / sum

  const int tid = threadIdx.x;
  const int wave = tid >> 6, lane = tid & 63;
  const int l15 = lane & 15, l16 = lane >> 4;
  const int sxor = (l15 >> 1) & 3;
  const int scol = ((lane & 3) ^ ((lane >> 3) & 3)) * 8;

  const int bid = blockIdx.x;
  const int plane = (bid & 7) * 64 + (bid >> 5);
  const int mtile = (bid >> 3) & 3;
  const int m0 = mtile << 6;
  const size_t zo = (size_t)plane * 65536;
  const u16* As[3] = {kh + zo, kh + zo, kl + zo};
  const u16* Bs[3] = {qh + zo, ql + zo, qh + zo};

  auto stageL = [&](int db, int ks) {
    int seg = ks >> 3, k0 = (ks & 7) * 32;
    {
      const u16* gp = As[seg];
      int r = wave * 16 + (lane >> 2);
      const u16* src = gp + (size_t)(m0 + r) * 256 + k0 + scol;
      __builtin_amdgcn_global_load_lds(
          (const __attribute__((address_space(1))) unsigned*)src,
          (__attribute__((address_space(3))) unsigned*)(sA[db] + wave * 512), 16, 0, 0);
    }
    {
      const u16* gp = Bs[seg];
      #pragma unroll
      for (int c = 0; c < 4; ++c) {
        int chunk = wave + c * 4;
        int r = chunk * 16 + (lane >> 2);
        const u16* src = gp + (size_t)r * 256 + k0 + scol;
        __builtin_amdgcn_global_load_lds(
            (const __attribute__((address_space(1))) unsigned*)src,
            (__attribute__((address_space(3))) unsigned*)(sB[db] + chunk * 512), 16, 0, 0);
      }
    }
  };

  // ---- phase L: logits, double-buffered; wave owns 64 rows x cols [64w,64w+64) ----
  f32x4 acc[4][4] = {};
  stageL(0, 0);
  VM0; BAR; SCHED0;
  for (int ks = 0; ks < 24; ++ks) {
    int cur = ks & 1, nxt = cur ^ 1;
    short8 a[4], b[4];
    #pragma unroll
    for (int fi = 0; fi < 4; ++fi) {
      int ra = (fi * 16 + l15) * 4 + (l16 ^ sxor);
      a[fi] = ((const short8*)sA[cur])[ra];
    }
    #pragma unroll
    for (int fj = 0; fj < 4; ++fj) {
      int rb = ((wave * 64 + fj * 16 + l15)) * 4 + (l16 ^ sxor);
      b[fj] = ((const short8*)sB[cur])[rb];
    }
    if (ks < 23) stageL(nxt, ks + 1);
    BAR; LGKM0;
    #pragma unroll
    for (int fi = 0; fi < 4; ++fi)
      #pragma unroll
      for (int fj = 0; fj < 4; ++fj)
        acc[fi][fj] = __builtin_amdgcn_mfma_f32_16x16x32_bf16(a[fi], b[fj], acc[fi][fj], 0, 0, 0);
    if (ks < 23) VM0;
    BAR; SCHED0;
  }

  // ---- cross-wave softmax ----
  #pragma unroll
  for (int fi = 0; fi < 4; ++fi)
    #pragma unroll
    for (int rr = 0; rr < 4; ++rr) {
      float m = fmaxf(fmaxf(acc[fi][0][rr], acc[fi][1][rr]),
                      fmaxf(acc[fi][2][rr], acc[fi][3][rr]));
      #pragma unroll
      for (int sh = 1; sh < 16; sh <<= 1) m = fmaxf(m, __shfl_xor(m, sh));
      if (l15 == 0) red[0][wave][fi * 16 + l16 * 4 + rr] = m;
    }
  __syncthreads();
  #pragma unroll
  for (int fi = 0; fi < 4; ++fi)
    #pragma unroll
    for (int rr = 0; rr < 4; ++rr) {
      int i = fi * 16 + l16 * 4 + rr;
      float M = fmaxf(fmaxf(red[0][0][i], red[0][1][i]),
                      fmaxf(red[0][2][i], red[0][3][i]));
      float s = 0.f;
      #pragma unroll
      for (int fj = 0; fj < 4; ++fj) {
        float ev = __expf(acc[fi][fj][rr] - M);
        acc[fi][fj][rr] = ev;
        s += ev;
      }
      #pragma unroll
      for (int sh = 1; sh < 16; sh <<= 1) s += __shfl_xor(s, sh);
      if (l15 == 0) red[1][wave][i] = s;
    }
  __syncthreads();
  #pragma unroll
  for (int fi = 0; fi < 4; ++fi)
    #pragma unroll
    for (int rr = 0; rr < 4; ++rr) {
      int i = fi * 16 + l16 * 4 + rr;
      float S = (red[1][0][i] + red[1][1][i]) + (red[1][2][i] + red[1][3][i]);
      float inv = 1.0f / S;
      #pragma unroll
      for (int fj = 0; fj < 4; ++fj)
        sP[i * 276 + wave * 64 + fj * 16 + l15] = f2bf(acc[fi][fj][rr] * inv);
    }
  __syncthreads();   // P complete

  // ---- phase PV: attn = P @ vT^T, double-buffered vT staging ----
  const int wr2 = wave >> 1, wc2 = wave & 1;       // 2x2: 32 rows x 128 cols
  auto stageV = [&](int db, int ks) {
    int k0 = ks * 32;
    #pragma unroll
    for (int c = 0; c < 4; ++c) {
      int chunk = wave + c * 4;
      int r = chunk * 16 + (lane >> 2);
      const u16* src = vT + zo + (size_t)r * 256 + k0 + scol;
      __builtin_amdgcn_global_load_lds(
          (const __attribute__((address_space(1))) unsigned*)src,
          (__attribute__((address_space(3))) unsigned*)(sB[db] + chunk * 512), 16, 0, 0);
    }
  };
  f32x4 acc2[2][8] = {};
  stageV(0, 0);
  VM0; BAR; SCHED0;
  for (int ks = 0; ks < 8; ++ks) {
    int cur = ks & 1, nxt = cur ^ 1;
    int k0 = ks * 32;
    short8 a2[2], b2[8];
    #pragma unroll
    for (int i = 0; i < 2; ++i) {
      int prow = wr2 * 32 + i * 16 + l15;
      a2[i] = *(const short8*)(sP + prow * 276 + k0 + l16 * 8);
    }
    #pragma unroll
    for (int j = 0; j < 8; ++j) {
      int rb = (wc2 * 128 + j * 16 + l15) * 4 + (l16 ^ sxor);
      b2[j] = ((const short8*)sB[cur])[rb];
    }
    if (ks < 7) stageV(nxt, ks + 1);
    BAR; LGKM0;
    #pragma unroll
    for (int i = 0; i < 2; ++i)
      #pragma unroll
      for (int j = 0; j < 8; ++j)
        acc2[i][j] = __builtin_amdgcn_mfma_f32_16x16x32_bf16(a2[i], b2[j], acc2[i][j], 0, 0, 0);
    if (ks < 7) VM0;
    BAR; SCHED0;
  }

  // epilogue: attn[(b*256+i)][(h*256+d)] — normal stores (proj re-reads; L3 wanted)
  #pragma unroll
  for (int i = 0; i < 2; ++i)
    #pragma unroll
    for (int j = 0; j < 8; ++j)
      #pragma unroll
      for (int rr = 0; rr < 4; ++rr) {
        int gi = m0 + wr2 * 32 + i * 16 + l16 * 4 + rr;
        int gd = wc2 * 128 + j * 16 + l15;
        size_t row = (size_t)(plane >> 3) * 256 + gi;
        size_t col = (size_t)(plane & 7) * 256 + gd;
        aout[row * 2048 + col] = f2bf(acc2[i][j][rr]);
      }
}

// ---------- per-head 256x256 in-place transpose (k_hi, k_lo, v) ----------
__global__ void transpose_inplace(u16* __restrict__ kh, u16* __restrict__ kl,
                                  u16* __restrict__ v) {
  __shared__ u16 ta[64][66], tb[64][66];
  u16* base = (blockIdx.z == 0) ? kh : (blockIdx.z == 1) ? kl : v;
  u16* pl = base + (size_t)blockIdx.y * 65536;
  const int RA[10] = {0,1,2,3, 0,0,0,1,1,2};
  const int CA[10] = {0,1,2,3, 1,2,3,2,3,3};
  int p = blockIdx.x;
  int R = RA[p], C = CA[p];
  bool diag = (R == C);
  int tid = threadIdx.x;
  int r = tid >> 2, c0 = (tid & 3) * 16;

  const us8* sa = (const us8*)(pl + (size_t)(R * 64 + r) * 256 + C * 64 + c0);
  us8 a0 = sa[0], a1 = sa[1];
  #pragma unroll
  for (int s = 0; s < 8; ++s) { ta[r][c0 + s] = a0[s]; ta[r][c0 + 8 + s] = a1[s]; }
  if (!diag) {
    const us8* sb = (const us8*)(pl + (size_t)(C * 64 + r) * 256 + R * 64 + c0);
    us8 b0 = sb[0], b1 = sb[1];
    #pragma unroll
    for (int s = 0; s < 8; ++s) { tb[r][c0 + s] = b0[s]; tb[r][c0 + 8 + s] = b1[s]; }
  }
  __syncthreads();
  us8 o0, o1;
  #pragma unroll
  for (int s = 0; s < 8; ++s) { o0[s] = ta[c0 + s][r]; o1[s] = ta[c0 + 8 + s][r]; }
  us8* da = (us8*)(pl + (size_t)(C * 64 + r) * 256 + R * 64 + c0);
  da[0] = o0; da[1] = o1;
  if (!diag) {
    us8 p0, p1;
    #pragma unroll
    for (int s = 0; s < 8; ++s) { p0[s] = tb[c0 + s][r]; p1[s] = tb[c0 + 8 + s][r]; }
    us8* db = (us8*)(pl + (size_t)(R * 64 + r) * 256 + C * 64 + c0);
    db[0] = p0; db[1] = p1;
  }
}

extern "C" void kernel_launch(void* const* d_in, const int* in_sizes, int n_in,
                              void* d_out, int out_size, void* d_ws, size_t ws_size,
                              hipStream_t stream) {
  const float* x  = (const float*)d_in[0];   // [16384, 2048]
  const float* wq = (const float*)d_in[1];   // [6144, 2048]
  const float* wp = (const float*)d_in[2];   // [2048, 2048]
  const float* bp = (const float*)d_in[3];   // [2048]
  float* out = (float*)d_out;
  char* ws = (char*)d_ws;

  const size_t MB = 1ull << 20;
  const size_t NEED = 432 * MB;
  if (ws_size < NEED) {
    beacon_kernel<<<2048, 256, 0, stream>>>(out, (float)(ws_size >> 20), 16384 * 2048);
    return;
  }

  // persistent per-head tensors [0, 320 MiB)
  u16* q_hi = (u16*)(ws);
  u16* q_lo = (u16*)(ws + 64 * MB);
  u16* k_hi = (u16*)(ws + 128 * MB);
  u16* k_lo = (u16*)(ws + 192 * MB);
  u16* vbuf = (u16*)(ws + 256 * MB);
  // G1 phase window [320, 432 MiB)
  u16* x_hi = (u16*)(ws + 320 * MB);   // 64 MiB
  u16* w_hi = (u16*)(ws + 384 * MB);   // 24 MiB
  u16* w_lo = (u16*)(ws + 408 * MB);   // 24 MiB
  // attention phase (x, w dead after G1)
  u16* attn = (u16*)(ws + 320 * MB);   // 64 MiB (over dead x_hi)
  u16* wpb  = (u16*)(ws + 384 * MB);   //  8 MiB (over dead w_hi)

  split_kernel<<<8192, 256, 0, stream>>>(x,  x_hi, nullptr, 16384 * 2048 / 4);
  split_kernel<<<4096, 256, 0, stream>>>(wq, w_hi, w_lo, 6144 * 2048 / 4);

  // G1 qk: q,k = x_hi @ (w_hi | w_lo)^T  (2 K-segments of 32 BK=64 tiles)
  gemm256<0><<<1024, 512, 131072, stream>>>(
      x_hi, x_hi, w_hi, w_lo, 2048, 2048, 64, 5, 64,
      q_hi, q_lo, k_hi, k_lo, nullptr, nullptr, nullptr);
  // G1 v: v = x_hi @ wv_hi^T  (1 segment, 32 tiles)
  const u16* wv = w_hi + (size_t)4096 * 2048;
  gemm256<1><<<512, 512, 131072, stream>>>(
      x_hi, x_hi, wv, wv, 2048, 2048, 32, 5, 64,
      nullptr, nullptr, nullptr, nullptr, vbuf, nullptr, nullptr);

  // in-place per-head transpose of k (hi,lo) and v
  transpose_inplace<<<dim3(10, 512, 3), 256, 0, stream>>>(k_hi, k_lo, vbuf);

  // fused logits + softmax + PV over all 512 planes -> attn (XCD-local decode)
  fused_attn<<<2048, 256, 0, stream>>>(k_hi, k_lo, q_hi, q_lo, vbuf, attn);

  // proj: out = attn @ wp^T + bias
  split_kernel<<<2048, 256, 0, stream>>>(wp, wpb, nullptr, 2048 * 2048 / 4);
  gemm256<2><<<512, 512, 131072, stream>>>(
      attn, attn, wpb, wpb, 2048, 2048, 32, 5, 64,
      nullptr, nullptr, nullptr, nullptr, nullptr, out, bp);
}

// Round 14
// 1017.653 us; speedup vs baseline: 1.1803x; 1.1803x over previous
//
#include <hip/hip_runtime.h>
#include <hip/hip_bf16.h>

typedef unsigned short u16;
typedef __attribute__((ext_vector_type(4))) float f32x4;
typedef __attribute__((ext_vector_type(8))) short short8;
typedef __attribute__((ext_vector_type(8))) u16 us8;

// Geometry (fixed): B=64, N=256, DIM=2048, H=8, D=256; M=B*N=16384; qkvN=6144

__device__ __forceinline__ u16 f2bf(float f) {
  union { float f; unsigned u; } v; v.f = f;
  unsigned r = v.u + 0x7fffu + ((v.u >> 16) & 1u);   // RNE, finite inputs
  return (u16)(r >> 16);
}
__device__ __forceinline__ float bf2f(u16 h) {
  union { unsigned u; float f; } v; v.u = ((unsigned)h) << 16; return v.f;
}

__global__ void beacon_kernel(float* __restrict__ out, float val, int n) {
  int stride = gridDim.x * blockDim.x;
  for (int i = blockIdx.x * blockDim.x + threadIdx.x; i < n; i += stride)
    out[i] = val;
}

__global__ void split_kernel(const float* __restrict__ in, u16* __restrict__ hi,
                             u16* __restrict__ lo, int n4) {
  int stride = gridDim.x * blockDim.x;
  for (int i = blockIdx.x * blockDim.x + threadIdx.x; i < n4; i += stride) {
    f32x4 v = ((const f32x4*)in)[i];
    ushort4 h;
    h.x = f2bf(v[0]); h.y = f2bf(v[1]); h.z = f2bf(v[2]); h.w = f2bf(v[3]);
    ((ushort4*)hi)[i] = h;
    if (lo) {
      ushort4 l;
      l.x = f2bf(v[0] - bf2f(h.x)); l.y = f2bf(v[1] - bf2f(h.y));
      l.z = f2bf(v[2] - bf2f(h.z)); l.w = f2bf(v[3] - bf2f(h.w));
      ((ushort4*)lo)[i] = l;
    }
  }
}

#define SCHED0 __builtin_amdgcn_sched_barrier(0)
#define LGKM0 do { asm volatile("s_waitcnt lgkmcnt(0)" ::: "memory"); SCHED0; } while (0)
#define VM0 do { asm volatile("s_waitcnt vmcnt(0)" ::: "memory"); } while (0)
#define BAR __builtin_amdgcn_s_barrier()

// ====== 256x256 bf16 NT GEMM — 1 barrier/tile, compiler-scheduled reads ======
// v14: r6's staged bytes + buffer swap invariant, but the 6 inner barriers and
// explicit lgkmcnt(0)s are REMOVED: all 24 ds_read_b128 issue up front, the
// compiler inserts fine-grained lgkmcnt before each dependent MFMA (m97-style),
// so LDS-read cycles overlap MFMA cycles.  One VM0+BAR per tile preserves the
// r6 staging-safety argument: reads of buf[cur] are consumed (lgkm) before
// each wave's BAR; stages targeting buf[cur] issue only after that BAR.
// Per-acc K-accumulation order unchanged -> output bit-exact vs r6/r12.
template<int EPI>
__global__ __launch_bounds__(512, 2)
void gemm256(const u16* __restrict__ A0, const u16* __restrict__ A1,
             const u16* __restrict__ B0, const u16* __restrict__ B1,
             int ldA, int ldB, int ntiles, int segShift, int gridMx,
             u16* __restrict__ qh, u16* __restrict__ ql,
             u16* __restrict__ kh, u16* __restrict__ kl,
             u16* __restrict__ vv,
             float* __restrict__ fout, const float* __restrict__ bias) {
  extern __shared__ __align__(16) u16 lds[];   // 128 KiB: 2 dbuf x (A+B)[256][64]

  const int tid = threadIdx.x;
  const int w = tid >> 6, lane = tid & 63;
  const int wr = w >> 2, wcn = w & 3;          // 2M x 4N waves, 128x64 out each
  const int l15 = lane & 15, g = lane >> 4;
  const int rsw = l15 & 7;                     // read-side slot XOR (row&7)
  const int scol = (((tid & 7) ^ ((tid >> 3) & 7)) << 3);  // pre-swz src col

  int bid = blockIdx.x, cpx = gridDim.x >> 3;
  int swz = (bid & 7) * cpx + (bid >> 3);
  int m0 = (swz % gridMx) << 8;
  int n0 = (swz / gridMx) << 8;

  const u16* As[2] = {A0, A1};
  const u16* Bs[2] = {B0, B1};
  const int kmask = (1 << segShift) - 1;

  f32x4 acc[8][4] = {};

  auto stageA = [&](int db, const u16* Ab, int k0) {
    #pragma unroll
    for (int s = 0; s < 4; ++s) {
      const u16* src = Ab + (size_t)(m0 + s * 64 + (tid >> 3)) * ldA + k0 + scol;
      u16* dst = lds + db * 32768 + s * 4096 + tid * 8;
      __builtin_amdgcn_global_load_lds(
          (const __attribute__((address_space(1))) unsigned*)src,
          (__attribute__((address_space(3))) unsigned*)dst, 16, 0, 0);
    }
  };
  auto stageB = [&](int db, const u16* Bb, int k0) {
    #pragma unroll
    for (int s = 0; s < 4; ++s) {
      const u16* src = Bb + (size_t)(n0 + s * 64 + (tid >> 3)) * ldB + k0 + scol;
      u16* dst = lds + db * 32768 + 16384 + s * 4096 + tid * 8;
      __builtin_amdgcn_global_load_lds(
          (const __attribute__((address_space(1))) unsigned*)src,
          (__attribute__((address_space(3))) unsigned*)dst, 16, 0, 0);
    }
  };
  auto readA2 = [&](short8* out8, int db, int MH) {   // 8 x ds_read_b128
    #pragma unroll
    for (int f = 0; f < 4; ++f) {
      int row = wr * 128 + MH * 64 + f * 16 + l15;
      #pragma unroll
      for (int kk = 0; kk < 2; ++kk) {
        int sl = (kk * 4 + g) ^ rsw;
        out8[f * 2 + kk] = *(const short8*)(lds + db * 32768 + row * 64 + sl * 8);
      }
    }
  };
  auto readB2 = [&](short8* bf, int db, int NH) {      // 4 x ds_read_b128
    #pragma unroll
    for (int f = 0; f < 2; ++f) {
      int row = wcn * 64 + NH * 32 + f * 16 + l15;
      #pragma unroll
      for (int kk = 0; kk < 2; ++kk) {
        int sl = (kk * 4 + g) ^ rsw;
        bf[f * 2 + kk] = *(const short8*)(lds + db * 32768 + 16384 + row * 64 + sl * 8);
      }
    }
  };

#define MMA_QUAD(MH, NH, AF, BF)                                               \
  _Pragma("unroll") for (int f = 0; f < 4; ++f)                                \
    _Pragma("unroll") for (int j = 0; j < 2; ++j)                              \
      _Pragma("unroll") for (int kk = 0; kk < 2; ++kk)                         \
        acc[(MH) * 4 + f][(NH) * 2 + j] =                                      \
            __builtin_amdgcn_mfma_f32_16x16x32_bf16(                           \
                AF[f * 2 + kk], BF[j * 2 + kk],                                \
                acc[(MH) * 4 + f][(NH) * 2 + j], 0, 0, 0);

  const int T = ntiles;
  stageA(0, As[0], 0);
  stageB(0, Bs[0], 0);
  VM0;
  BAR; SCHED0;

  for (int t = 0; t < T; ++t) {
    int cur = t & 1, nxt = cur ^ 1;
    const bool more = (t + 1 < T);
    short8 aF0[8], aF1[8], bF0[4], bF1[4];
    readA2(aF0, cur, 0);
    readB2(bF0, cur, 0);
    readB2(bF1, cur, 1);
    readA2(aF1, cur, 1);
    if (more) {
      int t1 = t + 1;
      stageA(nxt, As[t1 >> segShift], (t1 & kmask) << 6);
      stageB(nxt, Bs[t1 >> segShift], (t1 & kmask) << 6);
    }
    __builtin_amdgcn_s_setprio(1);
    MMA_QUAD(0, 0, aF0, bF0);
    MMA_QUAD(0, 1, aF0, bF1);
    MMA_QUAD(1, 1, aF1, bF1);
    MMA_QUAD(1, 0, aF1, bF0);
    __builtin_amdgcn_s_setprio(0);
    if (more) {
      VM0;
      BAR; SCHED0;
    }
  }
#undef MMA_QUAD

  // epilogue: C/D layout (m89/m91): col = lane&15, row = (lane>>4)*4 + reg
  #pragma unroll
  for (int i = 0; i < 8; ++i)
    #pragma unroll
    for (int j = 0; j < 4; ++j)
      #pragma unroll
      for (int rr = 0; rr < 4; ++rr) {
        int gm = m0 + wr * 128 + i * 16 + g * 4 + rr;
        int gn = n0 + wcn * 64 + j * 16 + l15;
        float val = acc[i][j][rr];
        if constexpr (EPI == 0) {
          int b = gm >> 8, tok = gm & 255;
          int sel = gn >> 11, head = (gn >> 8) & 7, col = gn & 255;
          size_t addr = (((size_t)b * 8 + head) * 256 + tok) * 256 + col;
          u16 h = f2bf(val), lo = f2bf(val - bf2f(h));
          if (sel == 0) { qh[addr] = h; ql[addr] = lo; }
          else          { kh[addr] = h; kl[addr] = lo; }
        } else if constexpr (EPI == 1) {
          int b = gm >> 8, tok = gm & 255;
          int head = (gn >> 8) & 7, col = gn & 255;
          size_t addr = (((size_t)b * 8 + head) * 256 + tok) * 256 + col;
          vv[addr] = f2bf(val);
        } else {
          fout[(size_t)gm * 2048 + gn] = val + bias[gn];
        }
      }
}

// ====== fully fused attention: logits + cross-wave softmax + PV (r12 verbatim) ======
__global__ __launch_bounds__(256)
void fused_attn(const u16* __restrict__ kh, const u16* __restrict__ kl,
                const u16* __restrict__ qh, const u16* __restrict__ ql,
                const u16* __restrict__ vT, u16* __restrict__ aout) {
  __shared__ __align__(16) u16 sA[2][2048];       // 64x32 dbuf (k rows)
  __shared__ __align__(16) u16 sB[2][8192];       // 256x32 dbuf (q / vT)
  __shared__ __align__(16) u16 sP[64 * 276];      // P, padded
  __shared__ float red[2][4][64];                 // partial max / sum

  const int tid = threadIdx.x;
  const int wave = tid >> 6, lane = tid & 63;
  const int l15 = lane & 15, l16 = lane >> 4;
  const int sxor = (l15 >> 1) & 3;
  const int scol = ((lane & 3) ^ ((lane >> 3) & 3)) * 8;

  const int bid = blockIdx.x;
  const int plane = (bid & 7) * 64 + (bid >> 5);
  const int mtile = (bid >> 3) & 3;
  const int m0 = mtile << 6;
  const size_t zo = (size_t)plane * 65536;
  const u16* As[3] = {kh + zo, kh + zo, kl + zo};
  const u16* Bs[3] = {qh + zo, ql + zo, qh + zo};

  auto stageL = [&](int db, int ks) {
    int seg = ks >> 3, k0 = (ks & 7) * 32;
    {
      const u16* gp = As[seg];
      int r = wave * 16 + (lane >> 2);
      const u16* src = gp + (size_t)(m0 + r) * 256 + k0 + scol;
      __builtin_amdgcn_global_load_lds(
          (const __attribute__((address_space(1))) unsigned*)src,
          (__attribute__((address_space(3))) unsigned*)(sA[db] + wave * 512), 16, 0, 0);
    }
    {
      const u16* gp = Bs[seg];
      #pragma unroll
      for (int c = 0; c < 4; ++c) {
        int chunk = wave + c * 4;
        int r = chunk * 16 + (lane >> 2);
        const u16* src = gp + (size_t)r * 256 + k0 + scol;
        __builtin_amdgcn_global_load_lds(
            (const __attribute__((address_space(1))) unsigned*)src,
            (__attribute__((address_space(3))) unsigned*)(sB[db] + chunk * 512), 16, 0, 0);
      }
    }
  };

  // ---- phase L: logits, double-buffered; wave owns 64 rows x cols [64w,64w+64) ----
  f32x4 acc[4][4] = {};
  stageL(0, 0);
  VM0; BAR; SCHED0;
  for (int ks = 0; ks < 24; ++ks) {
    int cur = ks & 1, nxt = cur ^ 1;
    short8 a[4], b[4];
    #pragma unroll
    for (int fi = 0; fi < 4; ++fi) {
      int ra = (fi * 16 + l15) * 4 + (l16 ^ sxor);
      a[fi] = ((const short8*)sA[cur])[ra];
    }
    #pragma unroll
    for (int fj = 0; fj < 4; ++fj) {
      int rb = ((wave * 64 + fj * 16 + l15)) * 4 + (l16 ^ sxor);
      b[fj] = ((const short8*)sB[cur])[rb];
    }
    if (ks < 23) stageL(nxt, ks + 1);
    BAR; LGKM0;
    #pragma unroll
    for (int fi = 0; fi < 4; ++fi)
      #pragma unroll
      for (int fj = 0; fj < 4; ++fj)
        acc[fi][fj] = __builtin_amdgcn_mfma_f32_16x16x32_bf16(a[fi], b[fj], acc[fi][fj], 0, 0, 0);
    if (ks < 23) VM0;
    BAR; SCHED0;
  }

  // ---- cross-wave softmax ----
  #pragma unroll
  for (int fi = 0; fi < 4; ++fi)
    #pragma unroll
    for (int rr = 0; rr < 4; ++rr) {
      float m = fmaxf(fmaxf(acc[fi][0][rr], acc[fi][1][rr]),
                      fmaxf(acc[fi][2][rr], acc[fi][3][rr]));
      #pragma unroll
      for (int sh = 1; sh < 16; sh <<= 1) m = fmaxf(m, __shfl_xor(m, sh));
      if (l15 == 0) red[0][wave][fi * 16 + l16 * 4 + rr] = m;
    }
  __syncthreads();
  #pragma unroll
  for (int fi = 0; fi < 4; ++fi)
    #pragma unroll
    for (int rr = 0; rr < 4; ++rr) {
      int i = fi * 16 + l16 * 4 + rr;
      float M = fmaxf(fmaxf(red[0][0][i], red[0][1][i]),
                      fmaxf(red[0][2][i], red[0][3][i]));
      float s = 0.f;
      #pragma unroll
      for (int fj = 0; fj < 4; ++fj) {
        float ev = __expf(acc[fi][fj][rr] - M);
        acc[fi][fj][rr] = ev;
        s += ev;
      }
      #pragma unroll
      for (int sh = 1; sh < 16; sh <<= 1) s += __shfl_xor(s, sh);
      if (l15 == 0) red[1][wave][i] = s;
    }
  __syncthreads();
  #pragma unroll
  for (int fi = 0; fi < 4; ++fi)
    #pragma unroll
    for (int rr = 0; rr < 4; ++rr) {
      int i = fi * 16 + l16 * 4 + rr;
      float S = (red[1][0][i] + red[1][1][i]) + (red[1][2][i] + red[1][3][i]);
      float inv = 1.0f / S;
      #pragma unroll
      for (int fj = 0; fj < 4; ++fj)
        sP[i * 276 + wave * 64 + fj * 16 + l15] = f2bf(acc[fi][fj][rr] * inv);
    }
  __syncthreads();   // P complete

  // ---- phase PV: attn = P @ vT^T, double-buffered vT staging ----
  const int wr2 = wave >> 1, wc2 = wave & 1;       // 2x2: 32 rows x 128 cols
  auto stageV = [&](int db, int ks) {
    int k0 = ks * 32;
    #pragma unroll
    for (int c = 0; c < 4; ++c) {
      int chunk = wave + c * 4;
      int r = chunk * 16 + (lane >> 2);
      const u16* src = vT + zo + (size_t)r * 256 + k0 + scol;
      __builtin_amdgcn_global_load_lds(
          (const __attribute__((address_space(1))) unsigned*)src,
          (__attribute__((address_space(3))) unsigned*)(sB[db] + chunk * 512), 16, 0, 0);
    }
  };
  f32x4 acc2[2][8] = {};
  stageV(0, 0);
  VM0; BAR; SCHED0;
  for (int ks = 0; ks < 8; ++ks) {
    int cur = ks & 1, nxt = cur ^ 1;
    int k0 = ks * 32;
    short8 a2[2], b2[8];
    #pragma unroll
    for (int i = 0; i < 2; ++i) {
      int prow = wr2 * 32 + i * 16 + l15;
      a2[i] = *(const short8*)(sP + prow * 276 + k0 + l16 * 8);
    }
    #pragma unroll
    for (int j = 0; j < 8; ++j) {
      int rb = (wc2 * 128 + j * 16 + l15) * 4 + (l16 ^ sxor);
      b2[j] = ((const short8*)sB[cur])[rb];
    }
    if (ks < 7) stageV(nxt, ks + 1);
    BAR; LGKM0;
    #pragma unroll
    for (int i = 0; i < 2; ++i)
      #pragma unroll
      for (int j = 0; j < 8; ++j)
        acc2[i][j] = __builtin_amdgcn_mfma_f32_16x16x32_bf16(a2[i], b2[j], acc2[i][j], 0, 0, 0);
    if (ks < 7) VM0;
    BAR; SCHED0;
  }

  // epilogue: attn[(b*256+i)][(h*256+d)]
  #pragma unroll
  for (int i = 0; i < 2; ++i)
    #pragma unroll
    for (int j = 0; j < 8; ++j)
      #pragma unroll
      for (int rr = 0; rr < 4; ++rr) {
        int gi = m0 + wr2 * 32 + i * 16 + l16 * 4 + rr;
        int gd = wc2 * 128 + j * 16 + l15;
        size_t row = (size_t)(plane >> 3) * 256 + gi;
        size_t col = (size_t)(plane & 7) * 256 + gd;
        aout[row * 2048 + col] = f2bf(acc2[i][j][rr]);
      }
}

// ---------- per-head 256x256 in-place transpose (k_hi, k_lo, v) ----------
__global__ void transpose_inplace(u16* __restrict__ kh, u16* __restrict__ kl,
                                  u16* __restrict__ v) {
  __shared__ u16 ta[64][66], tb[64][66];
  u16* base = (blockIdx.z == 0) ? kh : (blockIdx.z == 1) ? kl : v;
  u16* pl = base + (size_t)blockIdx.y * 65536;
  const int RA[10] = {0,1,2,3, 0,0,0,1,1,2};
  const int CA[10] = {0,1,2,3, 1,2,3,2,3,3};
  int p = blockIdx.x;
  int R = RA[p], C = CA[p];
  bool diag = (R == C);
  int tid = threadIdx.x;
  int r = tid >> 2, c0 = (tid & 3) * 16;

  const us8* sa = (const us8*)(pl + (size_t)(R * 64 + r) * 256 + C * 64 + c0);
  us8 a0 = sa[0], a1 = sa[1];
  #pragma unroll
  for (int s = 0; s < 8; ++s) { ta[r][c0 + s] = a0[s]; ta[r][c0 + 8 + s] = a1[s]; }
  if (!diag) {
    const us8* sb = (const us8*)(pl + (size_t)(C * 64 + r) * 256 + R * 64 + c0);
    us8 b0 = sb[0], b1 = sb[1];
    #pragma unroll
    for (int s = 0; s < 8; ++s) { tb[r][c0 + s] = b0[s]; tb[r][c0 + 8 + s] = b1[s]; }
  }
  __syncthreads();
  us8 o0, o1;
  #pragma unroll
  for (int s = 0; s < 8; ++s) { o0[s] = ta[c0 + s][r]; o1[s] = ta[c0 + 8 + s][r]; }
  us8* da = (us8*)(pl + (size_t)(C * 64 + r) * 256 + R * 64 + c0);
  da[0] = o0; da[1] = o1;
  if (!diag) {
    us8 p0, p1;
    #pragma unroll
    for (int s = 0; s < 8; ++s) { p0[s] = tb[c0 + s][r]; p1[s] = tb[c0 + 8 + s][r]; }
    us8* db = (us8*)(pl + (size_t)(R * 64 + r) * 256 + C * 64 + c0);
    db[0] = p0; db[1] = p1;
  }
}

extern "C" void kernel_launch(void* const* d_in, const int* in_sizes, int n_in,
                              void* d_out, int out_size, void* d_ws, size_t ws_size,
                              hipStream_t stream) {
  const float* x  = (const float*)d_in[0];   // [16384, 2048]
  const float* wq = (const float*)d_in[1];   // [6144, 2048]
  const float* wp = (const float*)d_in[2];   // [2048, 2048]
  const float* bp = (const float*)d_in[3];   // [2048]
  float* out = (float*)d_out;
  char* ws = (char*)d_ws;

  const size_t MB = 1ull << 20;
  const size_t NEED = 432 * MB;
  if (ws_size < NEED) {
    beacon_kernel<<<2048, 256, 0, stream>>>(out, (float)(ws_size >> 20), 16384 * 2048);
    return;
  }

  // persistent per-head tensors [0, 320 MiB)
  u16* q_hi = (u16*)(ws);
  u16* q_lo = (u16*)(ws + 64 * MB);
  u16* k_hi = (u16*)(ws + 128 * MB);
  u16* k_lo = (u16*)(ws + 192 * MB);
  u16* vbuf = (u16*)(ws + 256 * MB);
  // G1 phase window [320, 432 MiB)
  u16* x_hi = (u16*)(ws + 320 * MB);   // 64 MiB
  u16* w_hi = (u16*)(ws + 384 * MB);   // 24 MiB
  u16* w_lo = (u16*)(ws + 408 * MB);   // 24 MiB
  // attention phase (x, w dead after G1)
  u16* attn = (u16*)(ws + 320 * MB);   // 64 MiB (over dead x_hi)
  u16* wpb  = (u16*)(ws + 384 * MB);   //  8 MiB (over dead w_hi)

  split_kernel<<<8192, 256, 0, stream>>>(x,  x_hi, nullptr, 16384 * 2048 / 4);
  split_kernel<<<4096, 256, 0, stream>>>(wq, w_hi, w_lo, 6144 * 2048 / 4);

  // G1 qk: q,k = x_hi @ (w_hi | w_lo)^T  (2 K-segments of 32 BK=64 tiles)
  gemm256<0><<<1024, 512, 131072, stream>>>(
      x_hi, x_hi, w_hi, w_lo, 2048, 2048, 64, 5, 64,
      q_hi, q_lo, k_hi, k_lo, nullptr, nullptr, nullptr);
  // G1 v: v = x_hi @ wv_hi^T  (1 segment, 32 tiles)
  const u16* wv = w_hi + (size_t)4096 * 2048;
  gemm256<1><<<512, 512, 131072, stream>>>(
      x_hi, x_hi, wv, wv, 2048, 2048, 32, 5, 64,
      nullptr, nullptr, nullptr, nullptr, vbuf, nullptr, nullptr);

  // in-place per-head transpose of k (hi,lo) and v
  transpose_inplace<<<dim3(10, 512, 3), 256, 0, stream>>>(k_hi, k_lo, vbuf);

  // fused logits + softmax + PV over all 512 planes -> attn (XCD-local decode)
  fused_attn<<<2048, 256, 0, stream>>>(k_hi, k_lo, q_hi, q_lo, vbuf, attn);

  // proj: out = attn @ wp^T + bias
  split_kernel<<<2048, 256, 0, stream>>>(wp, wpb, nullptr, 2048 * 2048 / 4);
  gemm256<2><<<512, 512, 131072, stream>>>(
      attn, attn, wpb, wpb, 2048, 2048, 32, 5, 64,
      nullptr, nullptr, nullptr, nullptr, nullptr, out, bp);
}